// Round 2
// baseline (637.089 us; speedup 1.0000x reference)
//
#include <hip/hip_runtime.h>
#include <hip/hip_bf16.h>
#include <cstdint>

typedef __attribute__((ext_vector_type(8))) short bf16x8;
typedef __attribute__((ext_vector_type(4))) float f32x4;
typedef unsigned short u16;
typedef unsigned int u32;

#define MFMA16(a, b, c) __builtin_amdgcn_mfma_f32_16x16x32_bf16(a, b, c, 0, 0, 0)

__device__ __forceinline__ u16 f2bf(float f) {
  u32 u = __builtin_bit_cast(u32, f);
  u32 r = (u + 0x7fffu + ((u >> 16) & 1u)) >> 16;
  return (u16)r;
}

__device__ __forceinline__ void gload_lds16(const u16* g, u16* l) {
#if __has_builtin(__builtin_amdgcn_global_load_lds)
  __builtin_amdgcn_global_load_lds(
      (const __attribute__((address_space(1))) u32*)(const void*)g,
      (__attribute__((address_space(3))) u32*)(void*)l, 16, 0, 0);
#else
  *(uint4*)l = *(const uint4*)g;
#endif
}

// ---------------- prep kernels ----------------

__global__ __launch_bounds__(256) void cvt_x_kernel(const float* __restrict__ in,
                                                    u16* __restrict__ out, int n4) {
  const int stride = gridDim.x * blockDim.x;
  for (int i = blockIdx.x * blockDim.x + threadIdx.x; i < n4; i += stride) {
    float4 v = ((const float4*)in)[i];
    ushort4 o;
    o.x = f2bf(v.x); o.y = f2bf(v.y); o.z = f2bf(v.z); o.w = f2bf(v.w);
    ((ushort4*)out)[i] = o;
  }
}

// out[c*rows + r] = bf16(in[r*cols + c])  (i.e. out = in^T, bf16)
__global__ __launch_bounds__(256) void transpose_kernel(const float* __restrict__ in,
                                                        u16* __restrict__ out,
                                                        int rows, int cols) {
  int idx = blockIdx.x * 256 + threadIdx.x;
  if (idx < rows * cols) {
    int c = idx / rows, r = idx - c * rows;
    out[idx] = f2bf(in[(size_t)r * cols + c]);
  }
}

// ---------------- GEMM: C[M][N] = A[M][K] * Bt[N][K]^T + bias ----------------
// m97 structure: 128x128 tile, BK=64, 4 waves (2x2), global_load_lds width 16.

template <bool OUT_BF16>
__global__ __launch_bounds__(256) void gemm_bt(const u16* __restrict__ A,
                                               const u16* __restrict__ Bt,
                                               const float* __restrict__ bias,
                                               void* __restrict__ Cout, int Ncols) {
  constexpr int K = 512;
  const int tm = blockIdx.x, tn = blockIdx.y;
  const int t = threadIdx.x;
  const int lane = t & 63, w = t >> 6;
  const int wr = w >> 1, wc = w & 1;
  const int fr = lane & 15, fq = lane >> 4;

  __shared__ __align__(16) u16 Als[128 * 64];
  __shared__ __align__(16) u16 Bls[128 * 64];

  f32x4 acc[4][4] = {};

  const u16* Ab = A + (size_t)tm * 128 * K;
  const u16* Bb = Bt + (size_t)tn * 128 * K;
  const int srow = t >> 3;        // 0..31
  const int scol = (t & 7) * 8;   // element col within BK

  for (int ks = 0; ks < K; ks += 64) {
#pragma unroll
    for (int c = 0; c < 4; ++c) {
      gload_lds16(Ab + (size_t)(c * 32 + srow) * K + ks + scol, Als + c * 2048 + t * 8);
      gload_lds16(Bb + (size_t)(c * 32 + srow) * K + ks + scol, Bls + c * 2048 + t * 8);
    }
    __syncthreads();  // drains vmcnt(0) before barrier -> LDS tiles visible
#pragma unroll
    for (int kk = 0; kk < 2; ++kk) {
      bf16x8 af[4], bfr[4];
#pragma unroll
      for (int mt = 0; mt < 4; ++mt)
        af[mt] = *(const bf16x8*)(Als + (wr * 64 + mt * 16 + fr) * 64 + kk * 32 + fq * 8);
#pragma unroll
      for (int nt = 0; nt < 4; ++nt)
        bfr[nt] = *(const bf16x8*)(Bls + (wc * 64 + nt * 16 + fr) * 64 + kk * 32 + fq * 8);
#pragma unroll
      for (int mt = 0; mt < 4; ++mt)
#pragma unroll
        for (int nt = 0; nt < 4; ++nt)
          acc[mt][nt] = MFMA16(af[mt], bfr[nt], acc[mt][nt]);
    }
    __syncthreads();  // all waves done reading before next stage overwrites
  }

#pragma unroll
  for (int nt = 0; nt < 4; ++nt) {
    const int col = tn * 128 + wc * 64 + nt * 16 + fr;
    const float bv = bias[col];
#pragma unroll
    for (int mt = 0; mt < 4; ++mt) {
#pragma unroll
      for (int r = 0; r < 4; ++r) {
        const int row = tm * 128 + wr * 64 + mt * 16 + fq * 4 + r;
        float v = acc[mt][nt][r] + bv;
        if (OUT_BF16)
          ((u16*)Cout)[(size_t)row * Ncols + col] = f2bf(v);
        else
          ((float*)Cout)[(size_t)row * Ncols + col] = v;
      }
    }
  }
}

// ---------------- attention ----------------
// grid (256 token-blocks, 8 heads), 512 threads = 8 waves, 32 q-rows per wave.
// qkv layout: [token][s(0=q,1=k,2=v)*512 + h*64 + d], bf16.

__global__ __launch_bounds__(512) void attn_kernel(const u16* __restrict__ qkv,
                                                   u16* __restrict__ out) {
  const int p = blockIdx.x, h = blockIdx.y;
  const int t = threadIdx.x, lane = t & 63, w = t >> 6;
  const int fr = lane & 15, fq = lane >> 4;

  __shared__ __align__(16) u16 Kls[256][72];   // K rows, padded stride
  __shared__ __align__(16) u16 Vt[64][264];    // V transposed [d][token], padded
  __shared__ __align__(16) u16 Pls[8][32][72]; // per-wave P scratch

  const u16* base = qkv + (size_t)p * 256 * 1536 + h * 64;

  // stage K: 256 rows x 64 elems, 16B chunks
#pragma unroll
  for (int it = 0; it < 4; ++it) {
    int chunk = it * 512 + t;
    int row = chunk >> 3, c8 = (chunk & 7) * 8;
    *(uint4*)&Kls[row][c8] = *(const uint4*)(base + (size_t)row * 1536 + 512 + c8);
  }
  // stage V transposed: thread -> (token, d-half)
  {
    int token = t & 255, dh = (t >> 8) * 32;
    const u16* vs = base + (size_t)token * 1536 + 1024 + dh;
    uint4 b0 = *(const uint4*)(vs);
    uint4 b1 = *(const uint4*)(vs + 8);
    uint4 b2 = *(const uint4*)(vs + 16);
    uint4 b3 = *(const uint4*)(vs + 24);
    u16 tmp[32];
    *(uint4*)&tmp[0] = b0; *(uint4*)&tmp[8] = b1;
    *(uint4*)&tmp[16] = b2; *(uint4*)&tmp[24] = b3;
#pragma unroll
    for (int dd = 0; dd < 32; ++dd) Vt[dh + dd][token] = tmp[dd];
  }
  // Q fragments straight from global (A-operand layout)
  bf16x8 qf[2][2];
#pragma unroll
  for (int mt = 0; mt < 2; ++mt)
#pragma unroll
    for (int kk = 0; kk < 2; ++kk)
      qf[mt][kk] = *(const bf16x8*)(base + (size_t)(w * 32 + mt * 16 + fr) * 1536 + kk * 32 + fq * 8);
  __syncthreads();

  f32x4 Oc[2][4] = {};
  float mrow[2][4], lrow[2][4];
#pragma unroll
  for (int mt = 0; mt < 2; ++mt)
#pragma unroll
    for (int r = 0; r < 4; ++r) { mrow[mt][r] = -1e30f; lrow[mt][r] = 0.f; }

  for (int jb = 0; jb < 4; ++jb) {
    // S = Q K^T for 64-column block
    f32x4 S[2][4] = {};
#pragma unroll
    for (int kk = 0; kk < 2; ++kk) {
      bf16x8 kb[4];
#pragma unroll
      for (int jt = 0; jt < 4; ++jt)
        kb[jt] = *(const bf16x8*)&Kls[jb * 64 + jt * 16 + fr][kk * 32 + fq * 8];
#pragma unroll
      for (int mt = 0; mt < 2; ++mt)
#pragma unroll
        for (int jt = 0; jt < 4; ++jt)
          S[mt][jt] = MFMA16(qf[mt][kk], kb[jt], S[mt][jt]);
    }
    // online softmax (rows live on 16-lane groups; cols = lanes fr)
#pragma unroll
    for (int mt = 0; mt < 2; ++mt) {
#pragma unroll
      for (int r = 0; r < 4; ++r) {
        float s0 = S[mt][0][r] * 0.125f, s1 = S[mt][1][r] * 0.125f;
        float s2 = S[mt][2][r] * 0.125f, s3 = S[mt][3][r] * 0.125f;
        float mx = fmaxf(fmaxf(s0, s1), fmaxf(s2, s3));
#pragma unroll
        for (int d = 1; d < 16; d <<= 1) mx = fmaxf(mx, __shfl_xor(mx, d, 64));
        float mnew = fmaxf(mrow[mt][r], mx);
        float alpha = __expf(mrow[mt][r] - mnew);
        mrow[mt][r] = mnew;
        float e0 = __expf(s0 - mnew), e1 = __expf(s1 - mnew);
        float e2 = __expf(s2 - mnew), e3 = __expf(s3 - mnew);
        S[mt][0][r] = e0; S[mt][1][r] = e1; S[mt][2][r] = e2; S[mt][3][r] = e3;
        float rs = e0 + e1 + e2 + e3;
#pragma unroll
        for (int d = 1; d < 16; d <<= 1) rs += __shfl_xor(rs, d, 64);
        lrow[mt][r] = lrow[mt][r] * alpha + rs;
#pragma unroll
        for (int dt = 0; dt < 4; ++dt) Oc[mt][dt][r] *= alpha;
      }
    }
    // P: C-layout -> LDS -> A-layout
#pragma unroll
    for (int mt = 0; mt < 2; ++mt)
#pragma unroll
      for (int jt = 0; jt < 4; ++jt)
#pragma unroll
        for (int r = 0; r < 4; ++r)
          Pls[w][mt * 16 + fq * 4 + r][jt * 16 + fr] = f2bf(S[mt][jt][r]);
    __syncthreads();
    // O += P * V
#pragma unroll
    for (int kk = 0; kk < 2; ++kk) {
      bf16x8 pa[2], vb[4];
#pragma unroll
      for (int mt = 0; mt < 2; ++mt)
        pa[mt] = *(const bf16x8*)&Pls[w][mt * 16 + fr][kk * 32 + fq * 8];
#pragma unroll
      for (int dt = 0; dt < 4; ++dt)
        vb[dt] = *(const bf16x8*)&Vt[dt * 16 + fr][jb * 64 + kk * 32 + fq * 8];
#pragma unroll
      for (int mt = 0; mt < 2; ++mt)
#pragma unroll
        for (int dt = 0; dt < 4; ++dt)
          Oc[mt][dt] = MFMA16(pa[mt], vb[dt], Oc[mt][dt]);
    }
  }
  // normalize + store bf16
#pragma unroll
  for (int mt = 0; mt < 2; ++mt) {
#pragma unroll
    for (int r = 0; r < 4; ++r) {
      const float inv = 1.0f / lrow[mt][r];
      const int token = p * 256 + w * 32 + mt * 16 + fq * 4 + r;
#pragma unroll
      for (int dt = 0; dt < 4; ++dt)
        out[(size_t)token * 512 + h * 64 + dt * 16 + fr] = f2bf(Oc[mt][dt][r] * inv);
    }
  }
}

// ---------------- launcher ----------------

extern "C" void kernel_launch(void* const* d_in, const int* in_sizes, int n_in,
                              void* d_out, int out_size, void* d_ws, size_t ws_size,
                              hipStream_t stream) {
  const float* x      = (const float*)d_in[0];
  // d_in[1] = batch (unused: attention blocks of 256 tokens never straddle a batch boundary)
  const float* w_qkv  = (const float*)d_in[2];
  const float* b_qkv  = (const float*)d_in[3];
  const float* w_proj = (const float*)d_in[4];
  const float* b_proj = (const float*)d_in[5];

  char* ws = (char*)d_ws;
  u16* xa     = (u16*)ws;                  // 65536*512 bf16 = 64 MiB (reused as attn out)
  u16* wqkvT  = (u16*)(ws + 67108864);     // 1536*512 bf16
  u16* wprojT = (u16*)(ws + 68681728);     // 512*512 bf16
  u16* qkv    = (u16*)(ws + 69206016);     // 65536*1536 bf16 = 192 MiB
  u16* attn   = xa;                        // alias: x_bf16 dead after GEMM1

  cvt_x_kernel<<<2048, 256, 0, stream>>>(x, xa, 65536 * 512 / 4);
  transpose_kernel<<<(512 * 1536 + 255) / 256, 256, 0, stream>>>(w_qkv, wqkvT, 512, 1536);
  transpose_kernel<<<(512 * 512 + 255) / 256, 256, 0, stream>>>(w_proj, wprojT, 512, 512);

  gemm_bt<true><<<dim3(512, 12), 256, 0, stream>>>(xa, wqkvT, b_qkv, qkv, 1536);
  attn_kernel<<<dim3(256, 8), 512, 0, stream>>>(qkv, attn);
  gemm_bt<false><<<dim3(512, 4), 256, 0, stream>>>(attn, wprojT, b_proj, d_out, 512);
}

// Round 12
// 590.681 us; speedup vs baseline: 1.0786x; 1.0786x over previous
//
#include <hip/hip_runtime.h>
#include <hip/hip_bf16.h>
#include <cstdint>

typedef __attribute__((ext_vector_type(8))) short bf16x8;
typedef __attribute__((ext_vector_type(4))) float f32x4;
typedef unsigned short u16;
typedef unsigned int u32;

#define MFMA16(a, b, c) __builtin_amdgcn_mfma_f32_16x16x32_bf16(a, b, c, 0, 0, 0)

__device__ __forceinline__ u16 f2bf(float f) {
  u32 u = __builtin_bit_cast(u32, f);
  u32 r = (u + 0x7fffu + ((u >> 16) & 1u)) >> 16;
  return (u16)r;
}

__device__ __forceinline__ void gload_lds16(const u16* g, u16* l) {
  __builtin_amdgcn_global_load_lds(
      (const __attribute__((address_space(1))) u32*)(const void*)g,
      (__attribute__((address_space(3))) u32*)(void*)l, 16, 0, 0);
}

// ---------------- prep kernels (unchanged, known-good) ----------------

__global__ __launch_bounds__(256) void cvt_x_kernel(const float* __restrict__ in,
                                                    u16* __restrict__ out, int n4) {
  const int stride = gridDim.x * blockDim.x;
  for (int i = blockIdx.x * blockDim.x + threadIdx.x; i < n4; i += stride) {
    float4 v = ((const float4*)in)[i];
    ushort4 o;
    o.x = f2bf(v.x); o.y = f2bf(v.y); o.z = f2bf(v.z); o.w = f2bf(v.w);
    ((ushort4*)out)[i] = o;
  }
}

__global__ __launch_bounds__(256) void transpose_kernel(const float* __restrict__ in,
                                                        u16* __restrict__ out,
                                                        int rows, int cols) {
  int idx = blockIdx.x * 256 + threadIdx.x;
  if (idx < rows * cols) {
    int c = idx / rows, r = idx - c * rows;
    out[idx] = f2bf(in[(size_t)r * cols + c]);
  }
}

// ---------------- 256x256 8-phase GEMM (m201 template, plain HIP) ----------------
// C[M][N] = A[M][K=512] * Bt[N][K]^T + bias. 8 waves (2M x 4N), BK=64,
// LDS 128 KiB: lds[buf][op][half] = 2 x 2 x 2 x 16KiB. st_16x32 swizzle:
// linear gload_lds dest + inverse-swizzled GLOBAL source + swizzled ds_read.

template <bool OUT_BF16, int NTN>
__global__ __launch_bounds__(512, 2) void gemm8(const u16* __restrict__ A,
                                                const u16* __restrict__ Bt,
                                                const float* __restrict__ bias,
                                                void* __restrict__ Cout, int Ncols) {
  constexpr int K = 512;
  // bijective XCD chunk swizzle (nwg % 8 == 0 for both grids), tn-fastest
  const int nwg = gridDim.x;
  const int q8 = nwg >> 3;
  const int L = (blockIdx.x & 7) * q8 + (blockIdx.x >> 3);
  const int tm = L / NTN, tn = L % NTN;

  const int t = threadIdx.x, lane = t & 63, w = t >> 6;
  const int wr = w >> 2, wc = w & 3;          // 2 x 4 wave grid
  const int fr = lane & 15, fq = lane >> 4;

  __shared__ __align__(16) u16 lds[2][2][2][8192];  // [buf][A=0/B=1][half][16KiB]

  const u16* Ab = A + (size_t)tm * 256 * K;
  const u16* Bb = Bt + (size_t)tn * 256 * K;

  // staging chunk -> (row, col) inverse-swizzle map for this thread's 2 chunks
  int srow[2], scol[2];
#pragma unroll
  for (int i = 0; i < 2; ++i) {
    const int cidx = t + i * 512;
    const int rr = cidx >> 7, cc = (cidx >> 6) & 1, r16 = (cidx >> 2) & 15, qq = cidx & 3;
    const int c8 = qq ^ ((r16 >> 3) << 1);
    srow[i] = rr * 16 + r16;
    scol[i] = cc * 32 + c8 * 8;
  }

  f32x4 acc[8][4] = {};
  bf16x8 areg[4][2];   // current A subtile: 4 m-frags x 2 kk
  bf16x8 breg[4][2];   // current K-tile's B frags: 4 nt x 2 kk

  const int swz = (fq * 16) ^ ((fr & 8) << 2);  // swizzled col-byte within subtile

#define STAGE(SB, SOP, SH, STK)                                                  \
  {                                                                              \
    const u16* gb_ = (SOP == 0) ? Ab : Bb;                                       \
    u16* lb_ = &lds[SB][SOP][SH][0];                                             \
    _Pragma("unroll") for (int i_ = 0; i_ < 2; ++i_) {                           \
      gload_lds16(gb_ + (size_t)(SH * 128 + srow[i_]) * K + (STK) * 64 + scol[i_],\
                  lb_ + (t + i_ * 512) * 8);                                     \
    }                                                                            \
  }

#define LDA(RB, MH)                                                              \
  {                                                                              \
    const char* ab_ = (const char*)&lds[RB][0][wr][0];                           \
    _Pragma("unroll") for (int m_ = 0; m_ < 4; ++m_)                             \
      _Pragma("unroll") for (int kk_ = 0; kk_ < 2; ++kk_)                        \
        areg[m_][kk_] = *(const bf16x8*)(ab_ + ((MH) * 4 + m_) * 2048 +          \
                                         kk_ * 1024 + fr * 64 + swz);            \
  }

#define LDB(RB, NH)                                                              \
  {                                                                              \
    const char* bb_ = (const char*)&lds[RB][1][wc >> 1][0];                      \
    _Pragma("unroll") for (int n_ = 0; n_ < 2; ++n_)                             \
      _Pragma("unroll") for (int kk_ = 0; kk_ < 2; ++kk_)                        \
        breg[(NH) * 2 + n_][kk_] = *(const bf16x8*)(bb_ +                        \
            ((wc & 1) * 4 + (NH) * 2 + n_) * 2048 + kk_ * 1024 + fr * 64 + swz); \
  }

#define MMA(MH, NH)                                                              \
  {                                                                              \
    __builtin_amdgcn_s_setprio(1);                                               \
    _Pragma("unroll") for (int m_ = 0; m_ < 4; ++m_)                             \
      _Pragma("unroll") for (int n_ = 0; n_ < 2; ++n_)                           \
        _Pragma("unroll") for (int kk_ = 0; kk_ < 2; ++kk_)                      \
          acc[(MH) * 4 + m_][(NH) * 2 + n_] =                                    \
              MFMA16(areg[m_][kk_], breg[(NH) * 2 + n_][kk_],                    \
                     acc[(MH) * 4 + m_][(NH) * 2 + n_]);                         \
    __builtin_amdgcn_s_setprio(0);                                               \
  }

#define BAR() __builtin_amdgcn_s_barrier()
#define WLGKM() asm volatile("s_waitcnt lgkmcnt(0)" ::: "memory")
#define WV4() asm volatile("s_waitcnt vmcnt(4)" ::: "memory")
#define WV0() asm volatile("s_waitcnt vmcnt(0)" ::: "memory")

  // Prologue: T0 fully (B0,B1,A0,A1 -> buf0) + T1's B halves -> buf1.
  STAGE(0, 1, 0, 0) STAGE(0, 1, 1, 0) STAGE(0, 0, 0, 0) STAGE(0, 0, 1, 0)
  STAGE(1, 1, 0, 1) STAGE(1, 1, 1, 1)
  WV4();   // T0's 8 loads landed; T1-B's 4 may fly
  BAR();

  // Main: iterations s=0..2 compute T_{2s}(buf0), T_{2s+1}(buf1);
  // stage A(T_{2s+1})->buf1 @P1/P2, B(T_{2s+2})->buf0 @P3/P4,
  //       A(T_{2s+2})->buf0 @P5/P6, B(T_{2s+3})->buf1 @P7/P8.
  // Hazard proof: each region staged only after its last reader's
  // lgkmcnt(0)+barrier (B of cur read in P1-P2; A in P1,P3; prev-iter P7).
#pragma unroll 1
  for (int s = 0; s < 3; ++s) {
    const int o1 = 2 * s + 1, e2 = 2 * s + 2, o3 = 2 * s + 3;
    // P1
    LDA(0, 0) LDB(0, 0) STAGE(1, 0, 0, o1) BAR(); WLGKM(); MMA(0, 0) BAR();
    // P2
    LDB(0, 1) STAGE(1, 0, 1, o1) BAR(); WLGKM(); MMA(0, 1) BAR();
    // P3
    LDA(0, 1) STAGE(0, 1, 0, e2) BAR(); WLGKM(); MMA(1, 0) BAR();
    // P4  (vmcnt(4): P1/P2 stages landed -> buf1 A ready for P5)
    STAGE(0, 1, 1, e2) BAR(); MMA(1, 1) WV4(); BAR();
    // P5
    LDA(1, 0) LDB(1, 0) STAGE(0, 0, 0, e2) BAR(); WLGKM(); MMA(0, 0) BAR();
    // P6
    LDB(1, 1) STAGE(0, 0, 1, e2) BAR(); WLGKM(); MMA(0, 1) BAR();
    // P7
    LDA(1, 1) STAGE(1, 1, 0, o3) BAR(); WLGKM(); MMA(1, 0) BAR();
    // P8  (vmcnt(4): P3-P6 stages landed -> buf0 (T_{2s+2}) ready for next P1)
    STAGE(1, 1, 1, o3) BAR(); MMA(1, 1) WV4(); BAR();
  }
  // Epilogue iteration: compute T6(buf0), T7(buf1); stage only A(T7)->buf1.
  LDA(0, 0) LDB(0, 0) STAGE(1, 0, 0, 7) BAR(); WLGKM(); MMA(0, 0) BAR();
  LDB(0, 1) STAGE(1, 0, 1, 7) BAR(); WLGKM(); MMA(0, 1) BAR();
  LDA(0, 1) BAR(); WLGKM(); MMA(1, 0) BAR();
  BAR(); MMA(1, 1) WV0(); BAR();
  LDA(1, 0) LDB(1, 0) BAR(); WLGKM(); MMA(0, 0) BAR();
  LDB(1, 1) BAR(); WLGKM(); MMA(0, 1) BAR();
  LDA(1, 1) BAR(); WLGKM(); MMA(1, 0) BAR();
  MMA(1, 1)

  // C-write epilogue
#pragma unroll
  for (int nt = 0; nt < 4; ++nt) {
    const int col = tn * 256 + wc * 64 + nt * 16 + fr;
    const float bv = bias[col];
#pragma unroll
    for (int mt = 0; mt < 8; ++mt) {
#pragma unroll
      for (int r = 0; r < 4; ++r) {
        const int row = tm * 256 + wr * 128 + mt * 16 + fq * 4 + r;
        float v = acc[mt][nt][r] + bv;
        if (OUT_BF16)
          ((u16*)Cout)[(size_t)row * Ncols + col] = f2bf(v);
        else
          ((float*)Cout)[(size_t)row * Ncols + col] = v;
      }
    }
  }
#undef STAGE
#undef LDA
#undef LDB
#undef MMA
#undef BAR
#undef WLGKM
#undef WV4
#undef WV0
}

// ---------------- attention (unchanged, known-good) ----------------

__global__ __launch_bounds__(512) void attn_kernel(const u16* __restrict__ qkv,
                                                   u16* __restrict__ out) {
  const int p = blockIdx.x, h = blockIdx.y;
  const int t = threadIdx.x, lane = t & 63, w = t >> 6;
  const int fr = lane & 15, fq = lane >> 4;

  __shared__ __align__(16) u16 Kls[256][72];
  __shared__ __align__(16) u16 Vt[64][264];
  __shared__ __align__(16) u16 Pls[8][32][72];

  const u16* base = qkv + (size_t)p * 256 * 1536 + h * 64;

#pragma unroll
  for (int it = 0; it < 4; ++it) {
    int chunk = it * 512 + t;
    int row = chunk >> 3, c8 = (chunk & 7) * 8;
    *(uint4*)&Kls[row][c8] = *(const uint4*)(base + (size_t)row * 1536 + 512 + c8);
  }
  {
    int token = t & 255, dh = (t >> 8) * 32;
    const u16* vs = base + (size_t)token * 1536 + 1024 + dh;
    uint4 b0 = *(const uint4*)(vs);
    uint4 b1 = *(const uint4*)(vs + 8);
    uint4 b2 = *(const uint4*)(vs + 16);
    uint4 b3 = *(const uint4*)(vs + 24);
    u16 tmp[32];
    *(uint4*)&tmp[0] = b0; *(uint4*)&tmp[8] = b1;
    *(uint4*)&tmp[16] = b2; *(uint4*)&tmp[24] = b3;
#pragma unroll
    for (int dd = 0; dd < 32; ++dd) Vt[dh + dd][token] = tmp[dd];
  }
  bf16x8 qf[2][2];
#pragma unroll
  for (int mt = 0; mt < 2; ++mt)
#pragma unroll
    for (int kk = 0; kk < 2; ++kk)
      qf[mt][kk] = *(const bf16x8*)(base + (size_t)(w * 32 + mt * 16 + fr) * 1536 + kk * 32 + fq * 8);
  __syncthreads();

  f32x4 Oc[2][4] = {};
  float mrow[2][4], lrow[2][4];
#pragma unroll
  for (int mt = 0; mt < 2; ++mt)
#pragma unroll
    for (int r = 0; r < 4; ++r) { mrow[mt][r] = -1e30f; lrow[mt][r] = 0.f; }

  for (int jb = 0; jb < 4; ++jb) {
    f32x4 S[2][4] = {};
#pragma unroll
    for (int kk = 0; kk < 2; ++kk) {
      bf16x8 kb[4];
#pragma unroll
      for (int jt = 0; jt < 4; ++jt)
        kb[jt] = *(const bf16x8*)&Kls[jb * 64 + jt * 16 + fr][kk * 32 + fq * 8];
#pragma unroll
      for (int mt = 0; mt < 2; ++mt)
#pragma unroll
        for (int jt = 0; jt < 4; ++jt)
          S[mt][jt] = MFMA16(qf[mt][kk], kb[jt], S[mt][jt]);
    }
#pragma unroll
    for (int mt = 0; mt < 2; ++mt) {
#pragma unroll
      for (int r = 0; r < 4; ++r) {
        float s0 = S[mt][0][r] * 0.125f, s1 = S[mt][1][r] * 0.125f;
        float s2 = S[mt][2][r] * 0.125f, s3 = S[mt][3][r] * 0.125f;
        float mx = fmaxf(fmaxf(s0, s1), fmaxf(s2, s3));
#pragma unroll
        for (int d = 1; d < 16; d <<= 1) mx = fmaxf(mx, __shfl_xor(mx, d, 64));
        float mnew = fmaxf(mrow[mt][r], mx);
        float alpha = __expf(mrow[mt][r] - mnew);
        mrow[mt][r] = mnew;
        float e0 = __expf(s0 - mnew), e1 = __expf(s1 - mnew);
        float e2 = __expf(s2 - mnew), e3 = __expf(s3 - mnew);
        S[mt][0][r] = e0; S[mt][1][r] = e1; S[mt][2][r] = e2; S[mt][3][r] = e3;
        float rs = e0 + e1 + e2 + e3;
#pragma unroll
        for (int d = 1; d < 16; d <<= 1) rs += __shfl_xor(rs, d, 64);
        lrow[mt][r] = lrow[mt][r] * alpha + rs;
#pragma unroll
        for (int dt = 0; dt < 4; ++dt) Oc[mt][dt][r] *= alpha;
      }
    }
#pragma unroll
    for (int mt = 0; mt < 2; ++mt)
#pragma unroll
      for (int jt = 0; jt < 4; ++jt)
#pragma unroll
        for (int r = 0; r < 4; ++r)
          Pls[w][mt * 16 + fq * 4 + r][jt * 16 + fr] = f2bf(S[mt][jt][r]);
    __syncthreads();
#pragma unroll
    for (int kk = 0; kk < 2; ++kk) {
      bf16x8 pa[2], vb[4];
#pragma unroll
      for (int mt = 0; mt < 2; ++mt)
        pa[mt] = *(const bf16x8*)&Pls[w][mt * 16 + fr][kk * 32 + fq * 8];
#pragma unroll
      for (int dt = 0; dt < 4; ++dt)
        vb[dt] = *(const bf16x8*)&Vt[dt * 16 + fr][jb * 64 + kk * 32 + fq * 8];
#pragma unroll
      for (int mt = 0; mt < 2; ++mt)
#pragma unroll
        for (int dt = 0; dt < 4; ++dt)
          Oc[mt][dt] = MFMA16(pa[mt], vb[dt], Oc[mt][dt]);
    }
  }
#pragma unroll
  for (int mt = 0; mt < 2; ++mt) {
#pragma unroll
    for (int r = 0; r < 4; ++r) {
      const float inv = 1.0f / lrow[mt][r];
      const int token = p * 256 + w * 32 + mt * 16 + fq * 4 + r;
#pragma unroll
      for (int dt = 0; dt < 4; ++dt)
        out[(size_t)token * 512 + h * 64 + dt * 16 + fr] = f2bf(Oc[mt][dt][r] * inv);
    }
  }
}

// ---------------- launcher ----------------

extern "C" void kernel_launch(void* const* d_in, const int* in_sizes, int n_in,
                              void* d_out, int out_size, void* d_ws, size_t ws_size,
                              hipStream_t stream) {
  const float* x      = (const float*)d_in[0];
  const float* w_qkv  = (const float*)d_in[2];
  const float* b_qkv  = (const float*)d_in[3];
  const float* w_proj = (const float*)d_in[4];
  const float* b_proj = (const float*)d_in[5];

  char* ws = (char*)d_ws;
  u16* xa     = (u16*)ws;                  // 64 MiB (reused as attn out)
  u16* wqkvT  = (u16*)(ws + 67108864);
  u16* wprojT = (u16*)(ws + 68681728);
  u16* qkv    = (u16*)(ws + 69206016);     // 192 MiB
  u16* attn   = xa;

  cvt_x_kernel<<<2048, 256, 0, stream>>>(x, xa, 65536 * 512 / 4);
  transpose_kernel<<<(512 * 1536 + 255) / 256, 256, 0, stream>>>(w_qkv, wqkvT, 512, 1536);
  transpose_kernel<<<(512 * 512 + 255) / 256, 256, 0, stream>>>(w_proj, wprojT, 512, 512);

  gemm8<true, 6><<<1536, 512, 0, stream>>>(xa, wqkvT, b_qkv, qkv, 1536);
  attn_kernel<<<dim3(256, 8), 512, 0, stream>>>(qkv, attn);
  gemm8<false, 2><<<512, 512, 0, stream>>>(attn, wprojT, b_proj, d_out, 512);
}

// Round 13
// 541.773 us; speedup vs baseline: 1.1759x; 1.0903x over previous
//
#include <hip/hip_runtime.h>
#include <hip/hip_bf16.h>
#include <cstdint>

typedef __attribute__((ext_vector_type(8))) short bf16x8;
typedef __attribute__((ext_vector_type(4))) float f32x4;
typedef unsigned short u16;
typedef unsigned int u32;

#define MFMA16(a, b, c) __builtin_amdgcn_mfma_f32_16x16x32_bf16(a, b, c, 0, 0, 0)

__device__ __forceinline__ u16 f2bf(float f) {
  u32 u = __builtin_bit_cast(u32, f);
  u32 r = (u + 0x7fffu + ((u >> 16) & 1u)) >> 16;
  return (u16)r;
}

__device__ __forceinline__ void gload_lds16(const u16* g, u16* l) {
  __builtin_amdgcn_global_load_lds(
      (const __attribute__((address_space(1))) u32*)(const void*)g,
      (__attribute__((address_space(3))) u32*)(void*)l, 16, 0, 0);
}

// ---------------- prep kernels (unchanged, known-good) ----------------

__global__ __launch_bounds__(256) void cvt_x_kernel(const float* __restrict__ in,
                                                    u16* __restrict__ out, int n4) {
  const int stride = gridDim.x * blockDim.x;
  for (int i = blockIdx.x * blockDim.x + threadIdx.x; i < n4; i += stride) {
    float4 v = ((const float4*)in)[i];
    ushort4 o;
    o.x = f2bf(v.x); o.y = f2bf(v.y); o.z = f2bf(v.z); o.w = f2bf(v.w);
    ((ushort4*)out)[i] = o;
  }
}

__global__ __launch_bounds__(256) void transpose_kernel(const float* __restrict__ in,
                                                        u16* __restrict__ out,
                                                        int rows, int cols) {
  int idx = blockIdx.x * 256 + threadIdx.x;
  if (idx < rows * cols) {
    int c = idx / rows, r = idx - c * rows;
    out[idx] = f2bf(in[(size_t)r * cols + c]);
  }
}

// ---------------- 256x256 8-phase GEMM (unchanged from round 12, verified) ----------------
// 162 us QKV, MfmaUtil 26.5%, bank conflicts 0, FETCH near-ideal.

template <bool OUT_BF16, int NTN>
__global__ __launch_bounds__(512, 2) void gemm8(const u16* __restrict__ A,
                                                const u16* __restrict__ Bt,
                                                const float* __restrict__ bias,
                                                void* __restrict__ Cout, int Ncols) {
  constexpr int K = 512;
  const int nwg = gridDim.x;
  const int q8 = nwg >> 3;
  const int L = (blockIdx.x & 7) * q8 + (blockIdx.x >> 3);
  const int tm = L / NTN, tn = L % NTN;

  const int t = threadIdx.x, lane = t & 63, w = t >> 6;
  const int wr = w >> 2, wc = w & 3;
  const int fr = lane & 15, fq = lane >> 4;

  __shared__ __align__(16) u16 lds[2][2][2][8192];

  const u16* Ab = A + (size_t)tm * 256 * K;
  const u16* Bb = Bt + (size_t)tn * 256 * K;

  int srow[2], scol[2];
#pragma unroll
  for (int i = 0; i < 2; ++i) {
    const int cidx = t + i * 512;
    const int rr = cidx >> 7, cc = (cidx >> 6) & 1, r16 = (cidx >> 2) & 15, qq = cidx & 3;
    const int c8 = qq ^ ((r16 >> 3) << 1);
    srow[i] = rr * 16 + r16;
    scol[i] = cc * 32 + c8 * 8;
  }

  f32x4 acc[8][4] = {};
  bf16x8 areg[4][2];
  bf16x8 breg[4][2];

  const int swz = (fq * 16) ^ ((fr & 8) << 2);

#define STAGE(SB, SOP, SH, STK)                                                  \
  {                                                                              \
    const u16* gb_ = (SOP == 0) ? Ab : Bb;                                       \
    u16* lb_ = &lds[SB][SOP][SH][0];                                             \
    _Pragma("unroll") for (int i_ = 0; i_ < 2; ++i_) {                           \
      gload_lds16(gb_ + (size_t)(SH * 128 + srow[i_]) * K + (STK) * 64 + scol[i_],\
                  lb_ + (t + i_ * 512) * 8);                                     \
    }                                                                            \
  }

#define LDA(RB, MH)                                                              \
  {                                                                              \
    const char* ab_ = (const char*)&lds[RB][0][wr][0];                           \
    _Pragma("unroll") for (int m_ = 0; m_ < 4; ++m_)                             \
      _Pragma("unroll") for (int kk_ = 0; kk_ < 2; ++kk_)                        \
        areg[m_][kk_] = *(const bf16x8*)(ab_ + ((MH) * 4 + m_) * 2048 +          \
                                         kk_ * 1024 + fr * 64 + swz);            \
  }

#define LDB(RB, NH)                                                              \
  {                                                                              \
    const char* bb_ = (const char*)&lds[RB][1][wc >> 1][0];                      \
    _Pragma("unroll") for (int n_ = 0; n_ < 2; ++n_)                             \
      _Pragma("unroll") for (int kk_ = 0; kk_ < 2; ++kk_)                        \
        breg[(NH) * 2 + n_][kk_] = *(const bf16x8*)(bb_ +                        \
            ((wc & 1) * 4 + (NH) * 2 + n_) * 2048 + kk_ * 1024 + fr * 64 + swz); \
  }

#define MMA(MH, NH)                                                              \
  {                                                                              \
    __builtin_amdgcn_s_setprio(1);                                               \
    _Pragma("unroll") for (int m_ = 0; m_ < 4; ++m_)                             \
      _Pragma("unroll") for (int n_ = 0; n_ < 2; ++n_)                           \
        _Pragma("unroll") for (int kk_ = 0; kk_ < 2; ++kk_)                      \
          acc[(MH) * 4 + m_][(NH) * 2 + n_] =                                    \
              MFMA16(areg[m_][kk_], breg[(NH) * 2 + n_][kk_],                    \
                     acc[(MH) * 4 + m_][(NH) * 2 + n_]);                         \
    __builtin_amdgcn_s_setprio(0);                                               \
  }

#define BAR() __builtin_amdgcn_s_barrier()
#define WLGKM() asm volatile("s_waitcnt lgkmcnt(0)" ::: "memory")
#define WV4() asm volatile("s_waitcnt vmcnt(4)" ::: "memory")
#define WV0() asm volatile("s_waitcnt vmcnt(0)" ::: "memory")

  STAGE(0, 1, 0, 0) STAGE(0, 1, 1, 0) STAGE(0, 0, 0, 0) STAGE(0, 0, 1, 0)
  STAGE(1, 1, 0, 1) STAGE(1, 1, 1, 1)
  WV4();
  BAR();

#pragma unroll 1
  for (int s = 0; s < 3; ++s) {
    const int o1 = 2 * s + 1, e2 = 2 * s + 2, o3 = 2 * s + 3;
    LDA(0, 0) LDB(0, 0) STAGE(1, 0, 0, o1) BAR(); WLGKM(); MMA(0, 0) BAR();
    LDB(0, 1) STAGE(1, 0, 1, o1) BAR(); WLGKM(); MMA(0, 1) BAR();
    LDA(0, 1) STAGE(0, 1, 0, e2) BAR(); WLGKM(); MMA(1, 0) BAR();
    STAGE(0, 1, 1, e2) BAR(); MMA(1, 1) WV4(); BAR();
    LDA(1, 0) LDB(1, 0) STAGE(0, 0, 0, e2) BAR(); WLGKM(); MMA(0, 0) BAR();
    LDB(1, 1) STAGE(0, 0, 1, e2) BAR(); WLGKM(); MMA(0, 1) BAR();
    LDA(1, 1) STAGE(1, 1, 0, o3) BAR(); WLGKM(); MMA(1, 0) BAR();
    STAGE(1, 1, 1, o3) BAR(); MMA(1, 1) WV4(); BAR();
  }
  LDA(0, 0) LDB(0, 0) STAGE(1, 0, 0, 7) BAR(); WLGKM(); MMA(0, 0) BAR();
  LDB(0, 1) STAGE(1, 0, 1, 7) BAR(); WLGKM(); MMA(0, 1) BAR();
  LDA(0, 1) BAR(); WLGKM(); MMA(1, 0) BAR();
  BAR(); MMA(1, 1) WV0(); BAR();
  LDA(1, 0) LDB(1, 0) BAR(); WLGKM(); MMA(0, 0) BAR();
  LDB(1, 1) BAR(); WLGKM(); MMA(0, 1) BAR();
  LDA(1, 1) BAR(); WLGKM(); MMA(1, 0) BAR();
  MMA(1, 1)

#pragma unroll
  for (int nt = 0; nt < 4; ++nt) {
    const int col = tn * 256 + wc * 64 + nt * 16 + fr;
    const float bv = bias[col];
#pragma unroll
    for (int mt = 0; mt < 8; ++mt) {
#pragma unroll
      for (int r = 0; r < 4; ++r) {
        const int row = tm * 256 + wr * 128 + mt * 16 + fq * 4 + r;
        float v = acc[mt][nt][r] + bv;
        if (OUT_BF16)
          ((u16*)Cout)[(size_t)row * Ncols + col] = f2bf(v);
        else
          ((float*)Cout)[(size_t)row * Ncols + col] = v;
      }
    }
  }
#undef STAGE
#undef LDA
#undef LDB
#undef MMA
#undef BAR
#undef WLGKM
#undef WV4
#undef WV0
}

// ---------------- attention v2: all-S-in-registers, single exact softmax ----------------
// All 256 K-rows already staged in LDS -> online softmax was pure overhead.
// Phase 1: all 32 QK^T MFMAs into S[2][16] (128 VGPR). Phase 2: one max-tree +
// one sum-tree per row, exp in place, NO per-tile Oc rescale. Phase 3: PV via
// per-wave Pls chunks (no __syncthreads needed: per-wave scratch, compiler
// orders ds ops via lgkmcnt). launch_bounds(512,2) -> 256 VGPR cap, est ~195.

__global__ __launch_bounds__(512, 2) void attn_kernel(const u16* __restrict__ qkv,
                                                      u16* __restrict__ out) {
  const int p = blockIdx.x, h = blockIdx.y;
  const int t = threadIdx.x, lane = t & 63, w = t >> 6;
  const int fr = lane & 15, fq = lane >> 4;

  __shared__ __align__(16) u16 Kls[256][72];
  __shared__ __align__(16) u16 Vt[64][264];
  __shared__ __align__(16) u16 Pls[8][32][72];

  const u16* base = qkv + (size_t)p * 256 * 1536 + h * 64;

  // stage K: 256 rows x 64 elems
#pragma unroll
  for (int it = 0; it < 4; ++it) {
    int chunk = it * 512 + t;
    int row = chunk >> 3, c8 = (chunk & 7) * 8;
    *(uint4*)&Kls[row][c8] = *(const uint4*)(base + (size_t)row * 1536 + 512 + c8);
  }
  // stage V transposed
  {
    int token = t & 255, dh = (t >> 8) * 32;
    const u16* vs = base + (size_t)token * 1536 + 1024 + dh;
    uint4 b0 = *(const uint4*)(vs);
    uint4 b1 = *(const uint4*)(vs + 8);
    uint4 b2 = *(const uint4*)(vs + 16);
    uint4 b3 = *(const uint4*)(vs + 24);
    u16 tmp[32];
    *(uint4*)&tmp[0] = b0; *(uint4*)&tmp[8] = b1;
    *(uint4*)&tmp[16] = b2; *(uint4*)&tmp[24] = b3;
#pragma unroll
    for (int dd = 0; dd < 32; ++dd) Vt[dh + dd][token] = tmp[dd];
  }
  // Q fragments from global
  bf16x8 qf[2][2];
#pragma unroll
  for (int mt = 0; mt < 2; ++mt)
#pragma unroll
    for (int kk = 0; kk < 2; ++kk)
      qf[mt][kk] = *(const bf16x8*)(base + (size_t)(w * 32 + mt * 16 + fr) * 1536 + kk * 32 + fq * 8);
  __syncthreads();

  // ---- Phase 1: full S = Q K^T (32 MFMAs back-to-back) ----
  f32x4 S[2][16] = {};
#pragma unroll
  for (int jb = 0; jb < 4; ++jb) {
#pragma unroll
    for (int kk = 0; kk < 2; ++kk) {
      bf16x8 kb[4];
#pragma unroll
      for (int jt = 0; jt < 4; ++jt)
        kb[jt] = *(const bf16x8*)&Kls[jb * 64 + jt * 16 + fr][kk * 32 + fq * 8];
#pragma unroll
      for (int mt = 0; mt < 2; ++mt)
#pragma unroll
        for (int jt = 0; jt < 4; ++jt)
          S[mt][jb * 4 + jt] = MFMA16(qf[mt][kk], kb[jt], S[mt][jb * 4 + jt]);
    }
  }

  // ---- Phase 2: exact softmax, one pass per row ----
  float lrow[2][4];
#pragma unroll
  for (int mt = 0; mt < 2; ++mt) {
#pragma unroll
    for (int r = 0; r < 4; ++r) {
      float v[16];
#pragma unroll
      for (int j = 0; j < 16; ++j) v[j] = S[mt][j][r] * 0.125f;
      // in-lane max tree (16 -> 1)
      float m8[8];
#pragma unroll
      for (int j = 0; j < 8; ++j) m8[j] = fmaxf(v[2 * j], v[2 * j + 1]);
      float m4a = fmaxf(m8[0], m8[1]), m4b = fmaxf(m8[2], m8[3]);
      float m4c = fmaxf(m8[4], m8[5]), m4d = fmaxf(m8[6], m8[7]);
      float mx = fmaxf(fmaxf(m4a, m4b), fmaxf(m4c, m4d));
      // cross-lane over fr (bits 0-3 only)
#pragma unroll
      for (int d = 1; d < 16; d <<= 1) mx = fmaxf(mx, __shfl_xor(mx, d, 64));
      // exp in place + in-lane sum tree
      float s8[8];
#pragma unroll
      for (int j = 0; j < 8; ++j) {
        float e0 = __expf(v[2 * j] - mx), e1 = __expf(v[2 * j + 1] - mx);
        S[mt][2 * j][r] = e0; S[mt][2 * j + 1][r] = e1;
        s8[j] = e0 + e1;
      }
      float s4a = s8[0] + s8[1], s4b = s8[2] + s8[3];
      float s4c = s8[4] + s8[5], s4d = s8[6] + s8[7];
      float sum = (s4a + s4b) + (s4c + s4d);
#pragma unroll
      for (int d = 1; d < 16; d <<= 1) sum += __shfl_xor(sum, d, 64);
      lrow[mt][r] = sum;
    }
  }

  // ---- Phase 3: O = P V (per-wave Pls round-trip, no block barrier) ----
  f32x4 Oc[2][4] = {};
#pragma unroll
  for (int jb = 0; jb < 4; ++jb) {
#pragma unroll
    for (int mt = 0; mt < 2; ++mt)
#pragma unroll
      for (int jt = 0; jt < 4; ++jt)
#pragma unroll
        for (int r = 0; r < 4; ++r)
          Pls[w][mt * 16 + fq * 4 + r][jt * 16 + fr] = f2bf(S[mt][jb * 4 + jt][r]);
#pragma unroll
    for (int kk = 0; kk < 2; ++kk) {
      bf16x8 pa[2], vb[4];
#pragma unroll
      for (int mt = 0; mt < 2; ++mt)
        pa[mt] = *(const bf16x8*)&Pls[w][mt * 16 + fr][kk * 32 + fq * 8];
#pragma unroll
      for (int dt = 0; dt < 4; ++dt)
        vb[dt] = *(const bf16x8*)&Vt[dt * 16 + fr][jb * 64 + kk * 32 + fq * 8];
#pragma unroll
      for (int mt = 0; mt < 2; ++mt)
#pragma unroll
        for (int dt = 0; dt < 4; ++dt)
          Oc[mt][dt] = MFMA16(pa[mt], vb[dt], Oc[mt][dt]);
    }
  }

  // normalize + store
#pragma unroll
  for (int mt = 0; mt < 2; ++mt) {
#pragma unroll
    for (int r = 0; r < 4; ++r) {
      const float inv = 1.0f / lrow[mt][r];
      const int token = p * 256 + w * 32 + mt * 16 + fq * 4 + r;
#pragma unroll
      for (int dt = 0; dt < 4; ++dt)
        out[(size_t)token * 512 + h * 64 + dt * 16 + fr] = f2bf(Oc[mt][dt][r] * inv);
    }
  }
}

// ---------------- launcher ----------------

extern "C" void kernel_launch(void* const* d_in, const int* in_sizes, int n_in,
                              void* d_out, int out_size, void* d_ws, size_t ws_size,
                              hipStream_t stream) {
  const float* x      = (const float*)d_in[0];
  const float* w_qkv  = (const float*)d_in[2];
  const float* b_qkv  = (const float*)d_in[3];
  const float* w_proj = (const float*)d_in[4];
  const float* b_proj = (const float*)d_in[5];

  char* ws = (char*)d_ws;
  u16* xa     = (u16*)ws;                  // 64 MiB (reused as attn out)
  u16* wqkvT  = (u16*)(ws + 67108864);
  u16* wprojT = (u16*)(ws + 68681728);
  u16* qkv    = (u16*)(ws + 69206016);     // 192 MiB
  u16* attn   = xa;

  cvt_x_kernel<<<2048, 256, 0, stream>>>(x, xa, 65536 * 512 / 4);
  transpose_kernel<<<(512 * 1536 + 255) / 256, 256, 0, stream>>>(w_qkv, wqkvT, 512, 1536);
  transpose_kernel<<<(512 * 512 + 255) / 256, 256, 0, stream>>>(w_proj, wprojT, 512, 512);

  gemm8<true, 6><<<1536, 512, 0, stream>>>(xa, wqkvT, b_qkv, qkv, 1536);
  attn_kernel<<<dim3(256, 8), 512, 0, stream>>>(qkv, attn);
  gemm8<false, 2><<<512, 512, 0, stream>>>(attn, wprojT, b_proj, d_out, 512);
}